// Round 2
// baseline (749.057 us; speedup 1.0000x reference)
//
#include <hip/hip_runtime.h>
#include <cstdint>
#include <cstddef>

typedef unsigned int   u32;
typedef unsigned short u16;

__device__ __forceinline__ float bf2f(u32 bits16) { return __uint_as_float(bits16 << 16); }
__device__ __forceinline__ u16 f2bf(float f) {
  u32 u = __float_as_uint(f);
  u = u + 0x7FFFu + ((u >> 16) & 1u);   // round-to-nearest-even
  return (u16)(u >> 16);
}
__device__ __forceinline__ u32 pk(float a, float b) {
  return (u32)f2bf(a) | ((u32)f2bf(b) << 16);
}
__device__ __forceinline__ float lo16(u32 w) { return bf2f(w & 0xFFFFu); }
__device__ __forceinline__ float hi16(u32 w) { return bf2f(w >> 16); }
__device__ __forceinline__ float frcp(float x) { return __builtin_amdgcn_rcpf(x); }

__device__ __forceinline__ int load_idx(const int* eidx, int is64, long long pos) {
  if (is64) return (int)(((const long long*)eidx)[pos]);
  return eidx[pos];
}

// ---- prep stage 1 (grid 34): WcTmp = Wvl_left @ Wvv, edge-width detect, bc ----
__global__ void k_prep1(const float* Wvl, const float* Wvv,
                        const float* bvv, const float* bvl,
                        const int* eidx, int E, int* flag,
                        float* WcTmp, float* bc) {
  int b = blockIdx.x, tid = threadIdx.x;
  if (b < 32) {
    int c = 2 * b + (tid >> 7), kk = tid & 127;
    float s = 0.f;
    for (int m = 0; m < 64; ++m) s += Wvl[c * 128 + m] * Wvv[m * 128 + kk];
    WcTmp[c * 128 + kk] = s;
  } else if (b == 32) {
    __shared__ int zc;
    if (tid == 0) zc = 0;
    __syncthreads();
    int n = (E < 1024) ? E : 1024;
    int local = 0;
    for (int i = tid; i < n; i += 256) {
      if (eidx[2 * i + 1] == 0) local++;   // high words if int64 (all 0)
    }
    atomicAdd(&zc, local);
    __syncthreads();
    if (tid == 0) *flag = (zc >= (n >> 1)) ? 1 : 0;
  } else if (b == 33) {
    if (tid < 64) {
      float s = 0.f;
      for (int m = 0; m < 64; ++m) s += Wvl[tid * 128 + m] * bvv[m];
      bc[tid] = s + bvl[tid];
    }
  }
}

// ---- prep stage 2 (grid 11): bf16 epilogue tables + interleaved GEMM weight table ----
// Wsl2[(g*64+c)*2+h] = pack(Wsl[c][4g+2h], Wsl[c][4g+2h+1]), g<32
// Wpk : 2048 u32 : Wvl_right packed, same (g,c,h) layout, g<16
// WTall[((y*64+k)*64+c)*4+m]: m0=Wss[c][64y+k] m1=Wsv[..] m2=Wvs[..] m3=WcTmp[..]
__global__ void k_prep2(const float* Wss, const float* Wsv, const float* Wvs,
                        const float* Wsl, const float* Wvl, const float* WcTmp,
                        u32* Wsl2, u32* Wpk, float* WTall) {
  int b = blockIdx.x, tid = threadIdx.x;
  if (b < 2) {
    for (int i = 0; i < 8; ++i) {
      int o = b * 2048 + i * 256 + tid;
      int h = o & 1, c = (o >> 1) & 63, g = o >> 7;
      int k = 4 * g + 2 * h;
      Wsl2[o] = pk(Wsl[c * 128 + k], Wsl[c * 128 + k + 1]);
    }
  } else if (b == 2) {
    for (int i = 0; i < 8; ++i) {
      int o = i * 256 + tid;
      int h = o & 1, c = (o >> 1) & 63, g = o >> 7;
      int k = 4 * g + 2 * h;
      Wpk[o] = pk(Wvl[c * 128 + 64 + k], Wvl[c * 128 + 64 + k + 1]);
    }
  } else {
    for (int i = 0; i < 16; ++i) {
      int o = (b - 3) * 4096 + i * 256 + tid;
      int m = o & 3, c = (o >> 2) & 63, k = (o >> 8) & 63, y = o >> 14;
      int src = c * 128 + 64 * y + k;
      float v;
      if (m == 0)      v = Wss[src];
      else if (m == 1) v = Wsv[src];
      else if (m == 2) v = Wvs[src];
      else             v = WcTmp[src];
      WTall[o] = v;
    }
  }
}

__global__ void k_deg(const int* eidx, const int* flag, const float* attr,
                      float* deg, int* cnt, int E) {
  int e = blockIdx.x * 256 + threadIdx.x;
  if (e >= E) return;
  int is64 = *flag;
  int col = load_idx(eidx, is64, (long long)E + e);
  atomicAdd(&deg[col], attr[e]);
  atomicAdd(&cnt[col], 1);
}

// ---- multi-block exclusive scan of cnt -> rowptr, cursor ----
__global__ void k_scan_red(const int* cnt, int* blocksum, int N) {
  __shared__ int lds[256];
  int tid = threadIdx.x, idx = blockIdx.x * 256 + tid;
  lds[tid] = (idx < N) ? cnt[idx] : 0;
  __syncthreads();
  for (int off = 128; off > 0; off >>= 1) {
    if (tid < off) lds[tid] += lds[tid + off];
    __syncthreads();
  }
  if (tid == 0) blocksum[blockIdx.x] = lds[0];
}

__global__ void k_scan_mid(const int* blocksum, int* blockoff, int NB, int* rowptr, int N, int E) {
  __shared__ int lds[1024];
  int tid = threadIdx.x;
  int v = (tid < NB) ? blocksum[tid] : 0;
  lds[tid] = v;
  __syncthreads();
  for (int off = 1; off < 1024; off <<= 1) {
    int t = (tid >= off) ? lds[tid - off] : 0;
    __syncthreads();
    lds[tid] += t;
    __syncthreads();
  }
  if (tid < NB) blockoff[tid] = lds[tid] - v;   // exclusive
  if (tid == 0) rowptr[N] = E;
}

__global__ void k_scan_out(const int* cnt, const int* blockoff, int* rowptr, int* cursor, int N) {
  __shared__ int lds[256];
  int tid = threadIdx.x, idx = blockIdx.x * 256 + tid;
  int v = (idx < N) ? cnt[idx] : 0;
  lds[tid] = v;
  __syncthreads();
  for (int off = 1; off < 256; off <<= 1) {
    int t = (tid >= off) ? lds[tid - off] : 0;
    __syncthreads();
    lds[tid] += t;
    __syncthreads();
  }
  if (idx < N) {
    int o = blockoff[blockIdx.x] + lds[tid] - v;
    rowptr[idx] = o;
    cursor[idx] = o;
  }
}

// CSR fill: erecA[p]={norm, dx, dy, dz} (d = pos_i - pos_j), erecI[p]=row
__global__ void k_fill(const int* eidx, const int* flag, const float* attr, const float* deg,
                       const float* pos, int* cursor, float4* erecA, int* erecI, int E) {
  int e = blockIdx.x * 256 + threadIdx.x;
  if (e >= E) return;
  int is64 = *flag;
  int r  = load_idx(eidx, is64, e);
  int cl = load_idx(eidx, is64, (long long)E + e);
  float dr = deg[r], dc = deg[cl];
  float disr = (dr > 0.f) ? rsqrtf(dr) : 0.f;
  float disc = (dc > 0.f) ? rsqrtf(dc) : 0.f;
  float nrm = disr * disc * attr[e];
  float dx = pos[cl * 3 + 0] - pos[r * 3 + 0];
  float dy = pos[cl * 3 + 1] - pos[r * 3 + 1];
  float dz = pos[cl * 3 + 2] - pos[r * 3 + 2];
  int p = atomicAdd(&cursor[cl], 1);
  erecA[p] = make_float4(nrm, dx, dy, dz);
  erecI[p] = r;
}

// Fused node GEMM producing complete bf16 records with coalesced uint4 stores.
// grid (ceil(N/16), 2): y=0 -> rec_i {a_i,c_i,b_i,P_i}, y=1 -> rec_j {a_j,c_j,b_j,R_j}
// Per block: 16 nodes. LDS: X[k][n]={s,v0,v1,v2} (16KB) + W[k][c]={Wss,Wsv,Wvs,Wc} (64KB).
// Thread (n = tid>>4, channels 4*(tid&15)..+3): 32 fp32 accums, 32 fma / k-step.
__global__ __launch_bounds__(256) void k_gemm_rec(
    const float* __restrict__ scalar, const float* __restrict__ vector,
    const float* __restrict__ WTall,
    uint4* __restrict__ rec_i4, uint4* __restrict__ rec_j4, int N) {
  __shared__ float4 Xs[64 * 16];    // 16 KB
  __shared__ float4 Wsh[64 * 64];   // 64 KB
  int tid = threadIdx.x;
  int y = blockIdx.y;
  int nb = blockIdx.x * 16;
  float* Xw = (float*)Xs;

  // stage weights (contiguous copy, coalesced b128)
  const float4* Wg = (const float4*)WTall + (size_t)y * 4096;
  #pragma unroll
  for (int i = 0; i < 16; ++i) Wsh[i * 256 + tid] = Wg[i * 256 + tid];

  // stage scalar: 16 nodes x 64 k -> comp 0 of Xs[k][n]
  {
    int n = tid >> 4, kq = tid & 15;
    float4 v = make_float4(0.f, 0.f, 0.f, 0.f);
    if (nb + n < N) v = *(const float4*)(scalar + (size_t)(nb + n) * 64 + 4 * kq);
    Xw[((4 * kq + 0) * 16 + n) * 4 + 0] = v.x;
    Xw[((4 * kq + 1) * 16 + n) * 4 + 0] = v.y;
    Xw[((4 * kq + 2) * 16 + n) * 4 + 0] = v.z;
    Xw[((4 * kq + 3) * 16 + n) * 4 + 0] = v.w;
  }
  // stage vector: 16 nodes x 3 d x 64 k -> comps 1..3
  #pragma unroll
  for (int i = 0; i < 3; ++i) {
    int q = tid + i * 256;
    int r = q >> 4, kq = q & 15;
    int n = r / 3, d = r - n * 3;
    float4 v = make_float4(0.f, 0.f, 0.f, 0.f);
    if (nb + n < N) v = *(const float4*)(vector + (size_t)(nb + n) * 192 + d * 64 + 4 * kq);
    Xw[((4 * kq + 0) * 16 + n) * 4 + 1 + d] = v.x;
    Xw[((4 * kq + 1) * 16 + n) * 4 + 1 + d] = v.y;
    Xw[((4 * kq + 2) * 16 + n) * 4 + 1 + d] = v.z;
    Xw[((4 * kq + 3) * 16 + n) * 4 + 1 + d] = v.w;
  }
  __syncthreads();

  int cg = tid & 15, nl = tid >> 4;
  float aA[4] = {}, aC[4] = {};
  float aB[3][4] = {}, aP[3][4] = {};
  #pragma unroll 8
  for (int k = 0; k < 64; ++k) {
    float4 x = Xs[k * 16 + nl];
    #pragma unroll
    for (int j = 0; j < 4; ++j) {
      float4 w = Wsh[k * 64 + 4 * cg + j];
      aA[j]    = fmaf(x.x, w.x, aA[j]);
      aC[j]    = fmaf(x.x, w.y, aC[j]);
      aB[0][j] = fmaf(x.y, w.z, aB[0][j]);
      aB[1][j] = fmaf(x.z, w.z, aB[1][j]);
      aB[2][j] = fmaf(x.w, w.z, aB[2][j]);
      aP[0][j] = fmaf(x.y, w.w, aP[0][j]);
      aP[1][j] = fmaf(x.z, w.w, aP[1][j]);
      aP[2][j] = fmaf(x.w, w.w, aP[2][j]);
    }
  }

  int node = nb + nl;
  if (node < N) {
    uint4* dst = y ? rec_j4 : rec_i4;
    #pragma unroll
    for (int j = 0; j < 4; ++j) {
      int c = 4 * cg + j;
      uint4 o;
      o.x = pk(aA[j], aC[j]);
      o.y = pk(aB[0][j], aB[1][j]);
      o.z = pk(aB[2][j], aP[0][j]);
      o.w = pk(aP[1][j], aP[2][j]);
      dst[(size_t)node * 64 + c] = o;
    }
  }
}

// Fused hot kernel: one wave per node, wave-uniform scalar edge metadata,
// 2-edge unrolled loop with double prefetch, in-wave epilogue matvecs.
// Vector head: x-part (wa*Wc_i@v_i) precomputed as P_i in rec_i, y-part
// (Wc_j@v_j) precomputed as R_j in rec_j (edge-loop g-accumulators) ->
// only the nonlinear t-part remains as a 64-wide matvec.
__global__ __launch_bounds__(512) void k_edges(
    const u16* __restrict__ rec_i, const u16* __restrict__ rec_j,
    const float4* __restrict__ erecA, const int* __restrict__ erecI,
    const int* __restrict__ rowptr,
    const float* __restrict__ scalar, const float* __restrict__ vector,
    const float* __restrict__ bss, const float* __restrict__ bvs,
    const float* __restrict__ bsv, const float* __restrict__ bsl,
    const u32* __restrict__ Wsl2g, const u32* __restrict__ Wpkg,
    const float* __restrict__ bcg,
    float* __restrict__ out_s, float* __restrict__ out_v, int N) {
  __shared__ u32 sWsl[4096];        // 16 KB
  __shared__ u32 sWv[2048];         // 8 KB  (Wvl_right only)
  __shared__ float sStage[8 * 128]; // 4 KB, wave-private epilogue stage
  int tid = threadIdx.x, lane = tid & 63, wv = tid >> 6;
  for (int o = tid; o < 4096; o += 512) sWsl[o] = Wsl2g[o];
  for (int o = tid; o < 2048; o += 512) sWv[o] = Wpkg[o];
  __syncthreads();   // the only block barrier

  int node = __builtin_amdgcn_readfirstlane((int)(blockIdx.x * 8) + wv);
  if (node >= N) node = N - 1;

  uint4 riv = *(const uint4*)(rec_i + ((size_t)node << 9) + lane * 8);
  float aiB  = lo16(riv.x) + bss[lane];
  float ciB  = hi16(riv.x) + bsv[lane];
  float Bvs  = bvs[lane];
  float bib0 = lo16(riv.y) + Bvs;
  float bib1 = hi16(riv.y) + Bvs;
  float bib2 = lo16(riv.z) + Bvs;
  float Pi0  = hi16(riv.z), Pi1 = lo16(riv.w), Pi2 = hi16(riv.w);
  float bsl_c = bsl[lane], bc_c = bcg[lane];

  float us = 0, uv = 0, t0 = 0, t1 = 0, t2 = 0, g0 = 0, g1 = 0, g2 = 0, wa = 0;
  int rp = rowptr[node], re = rowptr[node + 1];
  u32 lim = (u32)(N - 1);
  u32 lane16 = (u32)lane << 4;
  const char* rjb = (const char*)rec_j;

  // erecI has 64 ints of slack past E; poison values clamp via min()
  u32 ra = min((u32)erecI[rp], lim);
  u32 rb = min((u32)erecI[rp + 1], lim);
  uint4 pre0 = *(const uint4*)(rjb + ((ra << 10) + lane16));
  uint4 pre1 = *(const uint4*)(rjb + ((rb << 10) + lane16));
  int p = rp;
  #define EDGE_MATH(CUR, EV)                                                  \
    {                                                                         \
      float nrm = EV.x, dx = EV.y, dy = EV.z, dz = EV.w;                      \
      float aj  = lo16(CUR.x), cj  = hi16(CUR.x);                             \
      float bj0 = lo16(CUR.y), bj1 = hi16(CUR.y), bj2 = lo16(CUR.z);          \
      float rj0 = hi16(CUR.z), rj1 = lo16(CUR.w), rj2 = hi16(CUR.w);          \
      float xs  = aiB + aj;                                                   \
      float s2s = xs * frcp(1.f + __expf(-xs));                               \
      float y   = (bib0 + bj0) * dx;                                          \
      y = fmaf(bib1 + bj1, dy, y);                                            \
      y = fmaf(bib2 + bj2, dz, y);                                            \
      float v2s = y * frcp(1.f + __expf(-y));                                 \
      float qh  = 2.8853900817779268f * (ciB + cj);                           \
      float th0 = fmaf(-2.f, frcp(1.f + exp2f(qh * dx)), 1.f);                \
      float th1 = fmaf(-2.f, frcp(1.f + exp2f(qh * dy)), 1.f);                \
      float th2 = fmaf(-2.f, frcp(1.f + exp2f(qh * dz)), 1.f);                \
      us = fmaf(nrm, s2s, us); uv = fmaf(nrm, v2s, uv);                       \
      t0 = fmaf(nrm, th0, t0); t1 = fmaf(nrm, th1, t1); t2 = fmaf(nrm, th2, t2);\
      g0 = fmaf(nrm, rj0, g0); g1 = fmaf(nrm, rj1, g1); g2 = fmaf(nrm, rj2, g2);\
      wa += nrm;                                                              \
    }
  for (; p + 1 < re; p += 2) {
    uint4 cur0 = pre0, cur1 = pre1;
    u32 rn0 = min((u32)erecI[p + 2], lim);
    u32 rn1 = min((u32)erecI[p + 3], lim);
    pre0 = *(const uint4*)(rjb + ((rn0 << 10) + lane16));
    pre1 = *(const uint4*)(rjb + ((rn1 << 10) + lane16));
    float4 e0 = erecA[p];
    float4 e1 = erecA[p + 1];
    EDGE_MATH(cur0, e0)
    EDGE_MATH(cur1, e1)
  }
  if (p < re) {
    uint4 cur0 = pre0;
    float4 e0 = erecA[p];
    EDGE_MATH(cur0, e0)
  }
  #undef EDGE_MATH

  // ---- epilogue: scalar head (wave-local, no block barrier) ----
  float* mys = &sStage[wv * 128];
  mys[lane] = us; mys[64 + lane] = uv;
  __threadfence_block();
  float acc = wa * bsl_c;
  #pragma unroll
  for (int g = 0; g < 32; ++g) {
    float4 u = *(const float4*)&mys[4 * g];
    uint2 w = *(const uint2*)&sWsl[(g * 64 + lane) * 2];
    acc = fmaf(u.x, lo16(w.x), acc);
    acc = fmaf(u.y, hi16(w.x), acc);
    acc = fmaf(u.z, lo16(w.y), acc);
    acc = fmaf(u.w, hi16(w.y), acc);
  }
  size_t so = ((size_t)node << 6) + lane;
  out_s[so] = acc * frcp(1.f + __expf(-acc)) + scalar[so];

  // ---- epilogue: vector head (t-part matvec only; x,y parts precomputed) ----
  float gg[3] = {g0, g1, g2}, tt[3] = {t0, t1, t2}, Pi[3] = {Pi0, Pi1, Pi2};
  #pragma unroll
  for (int d = 0; d < 3; ++d) {
    size_t vo = (((size_t)node * 3 + d) << 6) + lane;
    float vid = vector[vo];
    __threadfence_block();
    mys[lane] = tt[d];
    __threadfence_block();
    float a2 = fmaf(wa, bc_c + Pi[d], gg[d]);
    #pragma unroll
    for (int g = 0; g < 16; ++g) {
      float4 tu = *(const float4*)&mys[4 * g];
      uint2 w = *(const uint2*)&sWv[(g * 64 + lane) * 2];
      a2 = fmaf(tu.x, lo16(w.x), a2); a2 = fmaf(tu.y, hi16(w.x), a2);
      a2 = fmaf(tu.z, lo16(w.y), a2); a2 = fmaf(tu.w, hi16(w.y), a2);
    }
    float th = fmaf(-2.f, frcp(1.f + exp2f(2.8853900817779268f * a2)), 1.f);
    out_v[vo] = th + vid;
  }
}

extern "C" void kernel_launch(void* const* d_in, const int* in_sizes, int n_in,
                              void* d_out, int out_size, void* d_ws, size_t ws_size,
                              hipStream_t stream) {
  const float* scalar   = (const float*)d_in[0];
  const float* vector   = (const float*)d_in[1];
  const float* position = (const float*)d_in[2];
  const int*   eidx     = (const int*)d_in[3];
  const float* attr     = (const float*)d_in[4];
  const float* Wss = (const float*)d_in[5];
  const float* bss = (const float*)d_in[6];
  const float* Wvs = (const float*)d_in[7];
  const float* bvs = (const float*)d_in[8];
  const float* Wsl = (const float*)d_in[9];
  const float* bsl = (const float*)d_in[10];
  const float* Wsv = (const float*)d_in[11];
  const float* bsv = (const float*)d_in[12];
  const float* Wvv = (const float*)d_in[13];
  const float* bvv = (const float*)d_in[14];
  const float* Wvl = (const float*)d_in[15];
  const float* bvl = (const float*)d_in[16];

  int N = in_sizes[0] / 64;
  int E = in_sizes[4];
  int NB = (N + 255) / 256;   // scan blocks (must be <= 1024)

  char* wsb = (char*)d_ws;
  size_t off = 0;
  auto alloc = [&](size_t bytes) -> char* {
    char* p = wsb + off;
    off += (bytes + 255) & ~(size_t)255;
    return p;
  };
  float*  deg    = (float*)alloc((size_t)N * 4);
  int*    cnt    = (int*)alloc((size_t)N * 4);
  int*    rowptr = (int*)alloc((size_t)(N + 1) * 4);
  int*    cursor = (int*)alloc((size_t)N * 4);
  int*    blocksum = (int*)alloc((size_t)NB * 4);
  int*    blockoff = (int*)alloc((size_t)NB * 4);
  float4* erecA  = (float4*)alloc((size_t)E * 16);
  int*    erecI  = (int*)alloc((size_t)(E + 64) * 4);   // +slack for prefetch reads
  u16*    rec_i  = (u16*)alloc((size_t)N * 512 * 2);
  u16*    rec_j  = (u16*)alloc((size_t)N * 512 * 2);
  float*  WTall  = (float*)alloc(2 * 64 * 64 * 4 * 4);  // 128 KB interleaved weights
  u32*    Wsl2   = (u32*)alloc(4096 * 4);
  u32*    Wpk    = (u32*)alloc(2048 * 4);
  float*  WcTmp  = (float*)alloc(64 * 128 * 4);
  float*  bc     = (float*)alloc(64 * 4);
  int*    flag   = (int*)alloc(4);
  (void)ws_size; (void)n_in; (void)out_size;

  // zero deg + cnt (contiguous region)
  hipMemsetAsync(deg, 0, (size_t)((char*)rowptr - (char*)deg), stream);

  k_prep1<<<34, 256, 0, stream>>>(Wvl, Wvv, bvv, bvl, eidx, E, flag, WcTmp, bc);
  k_prep2<<<11, 256, 0, stream>>>(Wss, Wsv, Wvs, Wsl, Wvl, WcTmp, Wsl2, Wpk, WTall);
  k_deg<<<(E + 255) / 256, 256, 0, stream>>>(eidx, flag, attr, deg, cnt, E);
  k_scan_red<<<NB, 256, 0, stream>>>(cnt, blocksum, N);
  k_scan_mid<<<1, 1024, 0, stream>>>(blocksum, blockoff, NB, rowptr, N, E);
  k_scan_out<<<NB, 256, 0, stream>>>(cnt, blockoff, rowptr, cursor, N);
  k_fill<<<(E + 255) / 256, 256, 0, stream>>>(eidx, flag, attr, deg, position, cursor, erecA, erecI, E);
  dim3 gr((N + 15) / 16, 2);
  k_gemm_rec<<<gr, 256, 0, stream>>>(scalar, vector, WTall,
                                     (uint4*)rec_i, (uint4*)rec_j, N);
  k_edges<<<(N + 7) / 8, 512, 0, stream>>>(rec_i, rec_j, erecA, erecI, rowptr,
                                           scalar, vector, bss, bvs, bsv, bsl,
                                           Wsl2, Wpk, bc,
                                           (float*)d_out, (float*)d_out + (size_t)N * 64, N);
}

// Round 3
// 546.717 us; speedup vs baseline: 1.3701x; 1.3701x over previous
//
#include <hip/hip_runtime.h>
#include <cstdint>
#include <cstddef>

typedef unsigned int   u32;
typedef unsigned short u16;

__device__ __forceinline__ float bf2f(u32 bits16) { return __uint_as_float(bits16 << 16); }
__device__ __forceinline__ u16 f2bf(float f) {
  u32 u = __float_as_uint(f);
  u = u + 0x7FFFu + ((u >> 16) & 1u);   // round-to-nearest-even
  return (u16)(u >> 16);
}
__device__ __forceinline__ u32 pk(float a, float b) {
  return (u32)f2bf(a) | ((u32)f2bf(b) << 16);
}
__device__ __forceinline__ float lo16(u32 w) { return bf2f(w & 0xFFFFu); }
__device__ __forceinline__ float hi16(u32 w) { return bf2f(w >> 16); }
__device__ __forceinline__ float frcp(float x) { return __builtin_amdgcn_rcpf(x); }

__device__ __forceinline__ int load_idx(const int* eidx, int is64, long long pos) {
  if (is64) return (int)(((const long long*)eidx)[pos]);
  return eidx[pos];
}

// ---- prep stage 1 (grid 34): WcTmp = Wvl_left @ Wvv, edge-width detect, bc ----
__global__ void k_prep1(const float* Wvl, const float* Wvv,
                        const float* bvv, const float* bvl,
                        const int* eidx, int E, int* flag,
                        float* WcTmp, float* bc) {
  int b = blockIdx.x, tid = threadIdx.x;
  if (b < 32) {
    int c = 2 * b + (tid >> 7), kk = tid & 127;
    float s = 0.f;
    for (int m = 0; m < 64; ++m) s += Wvl[c * 128 + m] * Wvv[m * 128 + kk];
    WcTmp[c * 128 + kk] = s;
  } else if (b == 32) {
    __shared__ int zc;
    if (tid == 0) zc = 0;
    __syncthreads();
    int n = (E < 1024) ? E : 1024;
    int local = 0;
    for (int i = tid; i < n; i += 256) {
      if (eidx[2 * i + 1] == 0) local++;   // high words if int64 (all 0)
    }
    atomicAdd(&zc, local);
    __syncthreads();
    if (tid == 0) *flag = (zc >= (n >> 1)) ? 1 : 0;
  } else if (b == 33) {
    if (tid < 64) {
      float s = 0.f;
      for (int m = 0; m < 64; ++m) s += Wvl[tid * 128 + m] * bvv[m];
      bc[tid] = s + bvl[tid];
    }
  }
}

// ---- prep stage 2 (grid 11): bf16 epilogue tables + interleaved GEMM weight table ----
// Wsl2[(g*64+c)*2+h] = pack(Wsl[c][4g+2h], Wsl[c][4g+2h+1]), g<32
// Wpk : 2048 u32 : Wvl_right packed, same (g,c,h) layout, g<16
// WTall[((y*64+k)*64+c)*4+m]: m0=Wss[c][64y+k] m1=Wsv[..] m2=Wvs[..] m3=WcTmp[..]
__global__ void k_prep2(const float* Wss, const float* Wsv, const float* Wvs,
                        const float* Wsl, const float* Wvl, const float* WcTmp,
                        u32* Wsl2, u32* Wpk, float* WTall) {
  int b = blockIdx.x, tid = threadIdx.x;
  if (b < 2) {
    for (int i = 0; i < 8; ++i) {
      int o = b * 2048 + i * 256 + tid;
      int h = o & 1, c = (o >> 1) & 63, g = o >> 7;
      int k = 4 * g + 2 * h;
      Wsl2[o] = pk(Wsl[c * 128 + k], Wsl[c * 128 + k + 1]);
    }
  } else if (b == 2) {
    for (int i = 0; i < 8; ++i) {
      int o = i * 256 + tid;
      int h = o & 1, c = (o >> 1) & 63, g = o >> 7;
      int k = 4 * g + 2 * h;
      Wpk[o] = pk(Wvl[c * 128 + 64 + k], Wvl[c * 128 + 64 + k + 1]);
    }
  } else {
    for (int i = 0; i < 16; ++i) {
      int o = (b - 3) * 4096 + i * 256 + tid;
      int m = o & 3, c = (o >> 2) & 63, k = (o >> 8) & 63, y = o >> 14;
      int src = c * 128 + 64 * y + k;
      float v;
      if (m == 0)      v = Wss[src];
      else if (m == 1) v = Wsv[src];
      else if (m == 2) v = Wvs[src];
      else             v = WcTmp[src];
      WTall[o] = v;
    }
  }
}

__global__ void k_deg(const int* eidx, const int* flag, const float* attr,
                      float* deg, int* cnt, int E) {
  int e = blockIdx.x * 256 + threadIdx.x;
  if (e >= E) return;
  int is64 = *flag;
  int col = load_idx(eidx, is64, (long long)E + e);
  atomicAdd(&deg[col], attr[e]);
  atomicAdd(&cnt[col], 1);
}

// ---- multi-block exclusive scan of cnt -> rowptr, cursor ----
__global__ void k_scan_red(const int* cnt, int* blocksum, int N) {
  __shared__ int lds[256];
  int tid = threadIdx.x, idx = blockIdx.x * 256 + tid;
  lds[tid] = (idx < N) ? cnt[idx] : 0;
  __syncthreads();
  for (int off = 128; off > 0; off >>= 1) {
    if (tid < off) lds[tid] += lds[tid + off];
    __syncthreads();
  }
  if (tid == 0) blocksum[blockIdx.x] = lds[0];
}

__global__ void k_scan_mid(const int* blocksum, int* blockoff, int NB, int* rowptr, int N, int E) {
  __shared__ int lds[1024];
  int tid = threadIdx.x;
  int v = (tid < NB) ? blocksum[tid] : 0;
  lds[tid] = v;
  __syncthreads();
  for (int off = 1; off < 1024; off <<= 1) {
    int t = (tid >= off) ? lds[tid - off] : 0;
    __syncthreads();
    lds[tid] += t;
    __syncthreads();
  }
  if (tid < NB) blockoff[tid] = lds[tid] - v;   // exclusive
  if (tid == 0) rowptr[N] = E;
}

__global__ void k_scan_out(const int* cnt, const int* blockoff, int* rowptr, int* cursor, int N) {
  __shared__ int lds[256];
  int tid = threadIdx.x, idx = blockIdx.x * 256 + tid;
  int v = (idx < N) ? cnt[idx] : 0;
  lds[tid] = v;
  __syncthreads();
  for (int off = 1; off < 256; off <<= 1) {
    int t = (tid >= off) ? lds[tid - off] : 0;
    __syncthreads();
    lds[tid] += t;
    __syncthreads();
  }
  if (idx < N) {
    int o = blockoff[blockIdx.x] + lds[tid] - v;
    rowptr[idx] = o;
    cursor[idx] = o;
  }
}

// CSR fill: erecA[p]={norm, dx, dy, dz} (d = pos_i - pos_j), erecI[p]=row
__global__ void k_fill(const int* eidx, const int* flag, const float* attr, const float* deg,
                       const float* pos, int* cursor, float4* erecA, int* erecI, int E) {
  int e = blockIdx.x * 256 + threadIdx.x;
  if (e >= E) return;
  int is64 = *flag;
  int r  = load_idx(eidx, is64, e);
  int cl = load_idx(eidx, is64, (long long)E + e);
  float dr = deg[r], dc = deg[cl];
  float disr = (dr > 0.f) ? rsqrtf(dr) : 0.f;
  float disc = (dc > 0.f) ? rsqrtf(dc) : 0.f;
  float nrm = disr * disc * attr[e];
  float dx = pos[cl * 3 + 0] - pos[r * 3 + 0];
  float dy = pos[cl * 3 + 1] - pos[r * 3 + 1];
  float dz = pos[cl * 3 + 2] - pos[r * 3 + 2];
  int p = atomicAdd(&cursor[cl], 1);
  erecA[p] = make_float4(nrm, dx, dy, dz);
  erecI[p] = r;
}

// Fused node GEMM producing complete bf16 records with coalesced uint4 stores.
// grid (ceil(N/32), 2): y=0 -> rec_i {a_i,c_i,b_i,P_i}, y=1 -> rec_j {a_j,c_j,b_j,R_j}
// Block: 32 nodes, 256 threads. Thread (ng=tid>>4, cg=tid&15) owns nodes
// {ng, ng+16} x channels {cg, 16+cg, 32+cg, 48+cg} (remap kills bank conflicts).
// LDS: X SoA [comp][n][68-pad] fp32 (34 KB) + W k-half [32][64] float4 (32 KB).
__global__ __launch_bounds__(256) void k_gemm_rec(
    const float* __restrict__ scalar, const float* __restrict__ vector,
    const float* __restrict__ WTall,
    uint4* __restrict__ rec_i4, uint4* __restrict__ rec_j4, int N) {
  __shared__ float Xs_s[32][68];       // 8.5 KB
  __shared__ float Xs_v[3][32][68];    // 25.5 KB
  __shared__ float4 Wsh[32 * 64];      // 32 KB (one k-half)
  int tid = threadIdx.x;
  int y = blockIdx.y;
  int nb = blockIdx.x * 32;

  // stage X (all 64 k), b128 writes, coalesced b128 global reads
  #pragma unroll
  for (int i = 0; i < 2; ++i) {
    int q = tid + i * 256;            // q = n*16 + kq
    int n = q >> 4, kq = q & 15;
    float4 v = make_float4(0.f, 0.f, 0.f, 0.f);
    if (nb + n < N) v = *(const float4*)(scalar + (size_t)(nb + n) * 64 + 4 * kq);
    *(float4*)&Xs_s[n][4 * kq] = v;
  }
  #pragma unroll
  for (int i = 0; i < 6; ++i) {
    int q = tid + i * 256;            // q = (n*3+d)*16 + kq
    int r = q >> 4, kq = q & 15;
    int n = r / 3, d = r - n * 3;
    float4 v = make_float4(0.f, 0.f, 0.f, 0.f);
    if (nb + n < N) v = *(const float4*)(vector + (size_t)(nb + n) * 192 + d * 64 + 4 * kq);
    *(float4*)&Xs_v[d][n][4 * kq] = v;
  }

  int cg = tid & 15, ng = tid >> 4;
  float aA[2][4] = {}, aC[2][4] = {};
  float aB[2][3][4] = {}, aP[2][3][4] = {};
  const float4* Wg = (const float4*)WTall + (size_t)y * 4096;

  for (int kh = 0; kh < 2; ++kh) {
    __syncthreads();   // Wsh free (and X staged, first iter)
    #pragma unroll
    for (int i = 0; i < 8; ++i) Wsh[i * 256 + tid] = Wg[kh * 2048 + i * 256 + tid];
    __syncthreads();

    #pragma unroll 4
    for (int k4 = 0; k4 < 32; k4 += 4) {
      int kg = kh * 32 + k4;
      float4 xs[2], xv[2][3];
      #pragma unroll
      for (int r = 0; r < 2; ++r) {
        int n = ng + 16 * r;
        xs[r] = *(const float4*)&Xs_s[n][kg];
        #pragma unroll
        for (int d = 0; d < 3; ++d) xv[r][d] = *(const float4*)&Xs_v[d][n][kg];
      }
      #pragma unroll
      for (int t = 0; t < 4; ++t) {
        #pragma unroll
        for (int j = 0; j < 4; ++j) {
          float4 w = Wsh[(k4 + t) * 64 + 16 * j + cg];
          #pragma unroll
          for (int r = 0; r < 2; ++r) {
            float xsv = (t == 0) ? xs[r].x : (t == 1) ? xs[r].y : (t == 2) ? xs[r].z : xs[r].w;
            aA[r][j] = fmaf(xsv, w.x, aA[r][j]);
            aC[r][j] = fmaf(xsv, w.y, aC[r][j]);
            #pragma unroll
            for (int d = 0; d < 3; ++d) {
              float xvv = (t == 0) ? xv[r][d].x : (t == 1) ? xv[r][d].y : (t == 2) ? xv[r][d].z : xv[r][d].w;
              aB[r][d][j] = fmaf(xvv, w.z, aB[r][d][j]);
              aP[r][d][j] = fmaf(xvv, w.w, aP[r][d][j]);
            }
          }
        }
      }
    }
  }

  uint4* dst = y ? rec_j4 : rec_i4;
  #pragma unroll
  for (int r = 0; r < 2; ++r) {
    int node = nb + ng + 16 * r;
    if (node < N) {
      #pragma unroll
      for (int j = 0; j < 4; ++j) {
        int c = 16 * j + cg;
        uint4 o;
        o.x = pk(aA[r][j], aC[r][j]);
        o.y = pk(aB[r][0][j], aB[r][1][j]);
        o.z = pk(aB[r][2][j], aP[r][0][j]);
        o.w = pk(aP[r][1][j], aP[r][2][j]);
        dst[(size_t)node * 64 + c] = o;
      }
    }
  }
}

// Fused hot kernel: one wave per node, wave-uniform scalar edge metadata,
// 2-edge unrolled loop with double prefetch, in-wave epilogue matvecs.
// Vector head: x-part (wa*Wc_i@v_i) precomputed as P_i in rec_i, y-part
// (Wc_j@v_j) precomputed as R_j in rec_j (edge-loop g-accumulators) ->
// only the nonlinear t-part remains as a 64-wide matvec.
__global__ __launch_bounds__(512) void k_edges(
    const u16* __restrict__ rec_i, const u16* __restrict__ rec_j,
    const float4* __restrict__ erecA, const int* __restrict__ erecI,
    const int* __restrict__ rowptr,
    const float* __restrict__ scalar, const float* __restrict__ vector,
    const float* __restrict__ bss, const float* __restrict__ bvs,
    const float* __restrict__ bsv, const float* __restrict__ bsl,
    const u32* __restrict__ Wsl2g, const u32* __restrict__ Wpkg,
    const float* __restrict__ bcg,
    float* __restrict__ out_s, float* __restrict__ out_v, int N) {
  __shared__ u32 sWsl[4096];        // 16 KB
  __shared__ u32 sWv[2048];         // 8 KB  (Wvl_right only)
  __shared__ float sStage[8 * 128]; // 4 KB, wave-private epilogue stage
  int tid = threadIdx.x, lane = tid & 63, wv = tid >> 6;
  for (int o = tid; o < 4096; o += 512) sWsl[o] = Wsl2g[o];
  for (int o = tid; o < 2048; o += 512) sWv[o] = Wpkg[o];
  __syncthreads();   // the only block barrier

  int node = __builtin_amdgcn_readfirstlane((int)(blockIdx.x * 8) + wv);
  if (node >= N) node = N - 1;

  uint4 riv = *(const uint4*)(rec_i + ((size_t)node << 9) + lane * 8);
  float aiB  = lo16(riv.x) + bss[lane];
  float ciB  = hi16(riv.x) + bsv[lane];
  float Bvs  = bvs[lane];
  float bib0 = lo16(riv.y) + Bvs;
  float bib1 = hi16(riv.y) + Bvs;
  float bib2 = lo16(riv.z) + Bvs;
  float Pi0  = hi16(riv.z), Pi1 = lo16(riv.w), Pi2 = hi16(riv.w);
  float bsl_c = bsl[lane], bc_c = bcg[lane];

  float us = 0, uv = 0, t0 = 0, t1 = 0, t2 = 0, g0 = 0, g1 = 0, g2 = 0, wa = 0;
  int rp = rowptr[node], re = rowptr[node + 1];
  u32 lim = (u32)(N - 1);
  u32 lane16 = (u32)lane << 4;
  const char* rjb = (const char*)rec_j;

  // erecI has 64 ints of slack past E; poison values clamp via min()
  u32 ra = min((u32)erecI[rp], lim);
  u32 rb = min((u32)erecI[rp + 1], lim);
  uint4 pre0 = *(const uint4*)(rjb + ((ra << 10) + lane16));
  uint4 pre1 = *(const uint4*)(rjb + ((rb << 10) + lane16));
  int p = rp;
  #define EDGE_MATH(CUR, EV)                                                  \
    {                                                                         \
      float nrm = EV.x, dx = EV.y, dy = EV.z, dz = EV.w;                      \
      float aj  = lo16(CUR.x), cj  = hi16(CUR.x);                             \
      float bj0 = lo16(CUR.y), bj1 = hi16(CUR.y), bj2 = lo16(CUR.z);          \
      float rj0 = hi16(CUR.z), rj1 = lo16(CUR.w), rj2 = hi16(CUR.w);          \
      float xs  = aiB + aj;                                                   \
      float s2s = xs * frcp(1.f + __expf(-xs));                               \
      float y   = (bib0 + bj0) * dx;                                          \
      y = fmaf(bib1 + bj1, dy, y);                                            \
      y = fmaf(bib2 + bj2, dz, y);                                            \
      float v2s = y * frcp(1.f + __expf(-y));                                 \
      float qh  = 2.8853900817779268f * (ciB + cj);                           \
      float th0 = fmaf(-2.f, frcp(1.f + exp2f(qh * dx)), 1.f);                \
      float th1 = fmaf(-2.f, frcp(1.f + exp2f(qh * dy)), 1.f);                \
      float th2 = fmaf(-2.f, frcp(1.f + exp2f(qh * dz)), 1.f);                \
      us = fmaf(nrm, s2s, us); uv = fmaf(nrm, v2s, uv);                       \
      t0 = fmaf(nrm, th0, t0); t1 = fmaf(nrm, th1, t1); t2 = fmaf(nrm, th2, t2);\
      g0 = fmaf(nrm, rj0, g0); g1 = fmaf(nrm, rj1, g1); g2 = fmaf(nrm, rj2, g2);\
      wa += nrm;                                                              \
    }
  for (; p + 1 < re; p += 2) {
    uint4 cur0 = pre0, cur1 = pre1;
    u32 rn0 = min((u32)erecI[p + 2], lim);
    u32 rn1 = min((u32)erecI[p + 3], lim);
    pre0 = *(const uint4*)(rjb + ((rn0 << 10) + lane16));
    pre1 = *(const uint4*)(rjb + ((rn1 << 10) + lane16));
    float4 e0 = erecA[p];
    float4 e1 = erecA[p + 1];
    EDGE_MATH(cur0, e0)
    EDGE_MATH(cur1, e1)
  }
  if (p < re) {
    uint4 cur0 = pre0;
    float4 e0 = erecA[p];
    EDGE_MATH(cur0, e0)
  }
  #undef EDGE_MATH

  // ---- epilogue: scalar head (wave-local, no block barrier) ----
  float* mys = &sStage[wv * 128];
  mys[lane] = us; mys[64 + lane] = uv;
  __threadfence_block();
  float acc = wa * bsl_c;
  #pragma unroll
  for (int g = 0; g < 32; ++g) {
    float4 u = *(const float4*)&mys[4 * g];
    uint2 w = *(const uint2*)&sWsl[(g * 64 + lane) * 2];
    acc = fmaf(u.x, lo16(w.x), acc);
    acc = fmaf(u.y, hi16(w.x), acc);
    acc = fmaf(u.z, lo16(w.y), acc);
    acc = fmaf(u.w, hi16(w.y), acc);
  }
  size_t so = ((size_t)node << 6) + lane;
  out_s[so] = acc * frcp(1.f + __expf(-acc)) + scalar[so];

  // ---- epilogue: vector head (t-part matvec only; x,y parts precomputed) ----
  float gg[3] = {g0, g1, g2}, tt[3] = {t0, t1, t2}, Pi[3] = {Pi0, Pi1, Pi2};
  #pragma unroll
  for (int d = 0; d < 3; ++d) {
    size_t vo = (((size_t)node * 3 + d) << 6) + lane;
    float vid = vector[vo];
    __threadfence_block();
    mys[lane] = tt[d];
    __threadfence_block();
    float a2 = fmaf(wa, bc_c + Pi[d], gg[d]);
    #pragma unroll
    for (int g = 0; g < 16; ++g) {
      float4 tu = *(const float4*)&mys[4 * g];
      uint2 w = *(const uint2*)&sWv[(g * 64 + lane) * 2];
      a2 = fmaf(tu.x, lo16(w.x), a2); a2 = fmaf(tu.y, hi16(w.x), a2);
      a2 = fmaf(tu.z, lo16(w.y), a2); a2 = fmaf(tu.w, hi16(w.y), a2);
    }
    float th = fmaf(-2.f, frcp(1.f + exp2f(2.8853900817779268f * a2)), 1.f);
    out_v[vo] = th + vid;
  }
}

extern "C" void kernel_launch(void* const* d_in, const int* in_sizes, int n_in,
                              void* d_out, int out_size, void* d_ws, size_t ws_size,
                              hipStream_t stream) {
  const float* scalar   = (const float*)d_in[0];
  const float* vector   = (const float*)d_in[1];
  const float* position = (const float*)d_in[2];
  const int*   eidx     = (const int*)d_in[3];
  const float* attr     = (const float*)d_in[4];
  const float* Wss = (const float*)d_in[5];
  const float* bss = (const float*)d_in[6];
  const float* Wvs = (const float*)d_in[7];
  const float* bvs = (const float*)d_in[8];
  const float* Wsl = (const float*)d_in[9];
  const float* bsl = (const float*)d_in[10];
  const float* Wsv = (const float*)d_in[11];
  const float* bsv = (const float*)d_in[12];
  const float* Wvv = (const float*)d_in[13];
  const float* bvv = (const float*)d_in[14];
  const float* Wvl = (const float*)d_in[15];
  const float* bvl = (const float*)d_in[16];

  int N = in_sizes[0] / 64;
  int E = in_sizes[4];
  int NB = (N + 255) / 256;   // scan blocks (must be <= 1024)

  char* wsb = (char*)d_ws;
  size_t off = 0;
  auto alloc = [&](size_t bytes) -> char* {
    char* p = wsb + off;
    off += (bytes + 255) & ~(size_t)255;
    return p;
  };
  float*  deg    = (float*)alloc((size_t)N * 4);
  int*    cnt    = (int*)alloc((size_t)N * 4);
  int*    rowptr = (int*)alloc((size_t)(N + 1) * 4);
  int*    cursor = (int*)alloc((size_t)N * 4);
  int*    blocksum = (int*)alloc((size_t)NB * 4);
  int*    blockoff = (int*)alloc((size_t)NB * 4);
  float4* erecA  = (float4*)alloc((size_t)E * 16);
  int*    erecI  = (int*)alloc((size_t)(E + 64) * 4);   // +slack for prefetch reads
  u16*    rec_i  = (u16*)alloc((size_t)N * 512 * 2);
  u16*    rec_j  = (u16*)alloc((size_t)N * 512 * 2);
  float*  WTall  = (float*)alloc(2 * 64 * 64 * 4 * 4);  // 128 KB interleaved weights
  u32*    Wsl2   = (u32*)alloc(4096 * 4);
  u32*    Wpk    = (u32*)alloc(2048 * 4);
  float*  WcTmp  = (float*)alloc(64 * 128 * 4);
  float*  bc     = (float*)alloc(64 * 4);
  int*    flag   = (int*)alloc(4);
  (void)ws_size; (void)n_in; (void)out_size;

  // zero deg + cnt (contiguous region)
  hipMemsetAsync(deg, 0, (size_t)((char*)rowptr - (char*)deg), stream);

  k_prep1<<<34, 256, 0, stream>>>(Wvl, Wvv, bvv, bvl, eidx, E, flag, WcTmp, bc);
  k_prep2<<<11, 256, 0, stream>>>(Wss, Wsv, Wvs, Wsl, Wvl, WcTmp, Wsl2, Wpk, WTall);
  k_deg<<<(E + 255) / 256, 256, 0, stream>>>(eidx, flag, attr, deg, cnt, E);
  k_scan_red<<<NB, 256, 0, stream>>>(cnt, blocksum, N);
  k_scan_mid<<<1, 1024, 0, stream>>>(blocksum, blockoff, NB, rowptr, N, E);
  k_scan_out<<<NB, 256, 0, stream>>>(cnt, blockoff, rowptr, cursor, N);
  k_fill<<<(E + 255) / 256, 256, 0, stream>>>(eidx, flag, attr, deg, position, cursor, erecA, erecI, E);
  dim3 gr((N + 31) / 32, 2);
  k_gemm_rec<<<gr, 256, 0, stream>>>(scalar, vector, WTall,
                                     (uint4*)rec_i, (uint4*)rec_j, N);
  k_edges<<<(N + 7) / 8, 512, 0, stream>>>(rec_i, rec_j, erecA, erecI, rowptr,
                                           scalar, vector, bss, bvs, bsv, bsl,
                                           Wsl2, Wpk, bc,
                                           (float*)d_out, (float*)d_out + (size_t)N * 64, N);
}